// Round 12
// baseline (1724.674 us; speedup 1.0000x reference)
//
#include <hip/hip_runtime.h>
#include <hip/hip_bf16.h>
#include <stdint.h>

#define VOCAB 32000
#define HID 512
#define NB 8
#define SEQ 512
#define NG 1536
#define LN_EPS 1e-5f
#define GRU_WGS 32
#define HEATERS 224
#define GRU_SPIN_BUDGET (1 << 20)

typedef short bf16x8 __attribute__((ext_vector_type(8)));
typedef float f32x4 __attribute__((ext_vector_type(4)));

__device__ __forceinline__ unsigned short f2bf(float f) {
  union { float f; uint32_t u; } c; c.f = f;
  return (unsigned short)((c.u + 0x7fffu + ((c.u >> 16) & 1u)) >> 16);
}

// ---------------- init workspace (every launch: h_state=0, flags=0) ---------
__global__ void init_ws_kernel(unsigned short* h_state, int* flags) {
  int i = blockIdx.x * 256 + threadIdx.x;
  if (i < 2 * 16 * HID) h_state[i] = 0;
  if (i < GRU_WGS * 16) flags[i] = 0;
}

// ---------------- fp32 -> bf16 bulk convert ---------------------------------
__global__ void conv_bf16_kernel(const float* __restrict__ in,
                                 unsigned short* __restrict__ out, int n4) {
  int i = blockIdx.x * 256 + threadIdx.x;
  if (i >= n4) return;
  const float4 v = ((const float4*)in)[i];
  ushort4 o;
  o.x = f2bf(v.x); o.y = f2bf(v.y); o.z = f2bf(v.z); o.w = f2bf(v.w);
  ((ushort4*)out)[i] = o;
}

// ---------------- embedding gather -> bf16 A matrix [4096][512] -------------
__global__ void embed_kernel(const int* __restrict__ ids,
                             const float* __restrict__ emb,
                             unsigned short* __restrict__ out) {
  int row = blockIdx.x;
  int id = ids[row];
  int c = threadIdx.x * 2;
  const float2 v = *(const float2*)(emb + (size_t)id * HID + c);
  ushort2 o; o.x = f2bf(v.x); o.y = f2bf(v.y);
  *(ushort2*)(out + (size_t)row * HID + c) = o;
}

// ---------------- bf16 GEMM 128x128 (xg GEMM) --------------------------------
#define BM 128
#define BN 128
#define BK 32

__global__ __launch_bounds__(256, 2) void gemm_bt_kernel(
    const unsigned short* __restrict__ A, const unsigned short* __restrict__ B,
    const float* __restrict__ bias, float* __restrict__ C, int N, int nbn) {
  __shared__ unsigned short a_lds[BM * BK];
  __shared__ unsigned short b_lds[BN * BK];
  const int nwg = gridDim.x;
  const int chunk = nwg >> 3;
  const int bid = blockIdx.x;
  const int sw = (bid & 7) * chunk + (bid >> 3);
  const int bm = sw / nbn, bn = sw % nbn;
  const int tid = threadIdx.x;
  const int lane = tid & 63, wid = tid >> 6;
  const int wm = wid >> 1, wn = wid & 1;

  f32x4 acc[4][4] = {};

  for (int kt = 0; kt < HID / BK; ++kt) {
    __syncthreads();
#pragma unroll
    for (int p = 0; p < 2; ++p) {
      const int flat = (p * 256 + tid) * 16;
      const int row = flat >> 6;
      const int kb = flat & 63;
      const char* ga =
          (const char*)(A + ((size_t)(bm * BM + row) * HID + kt * BK)) + kb;
      const char* gb =
          (const char*)(B + ((size_t)(bn * BN + row) * HID + kt * BK)) + kb;
      char* la = (char*)a_lds + (size_t)(p * 256 + wid * 64) * 16;
      char* lb = (char*)b_lds + (size_t)(p * 256 + wid * 64) * 16;
      __builtin_amdgcn_global_load_lds(
          (const __attribute__((address_space(1))) void*)ga,
          (__attribute__((address_space(3))) void*)la, 16, 0, 0);
      __builtin_amdgcn_global_load_lds(
          (const __attribute__((address_space(1))) void*)gb,
          (__attribute__((address_space(3))) void*)lb, 16, 0, 0);
    }
    __syncthreads();
    bf16x8 af[4], bfr[4];
#pragma unroll
    for (int i = 0; i < 4; ++i) {
      af[i] = *(const bf16x8*)(a_lds + (wm * 64 + i * 16 + (lane & 15)) * BK +
                               (lane >> 4) * 8);
      bfr[i] = *(const bf16x8*)(b_lds + (wn * 64 + i * 16 + (lane & 15)) * BK +
                                (lane >> 4) * 8);
    }
#pragma unroll
    for (int i = 0; i < 4; ++i)
#pragma unroll
      for (int j = 0; j < 4; ++j)
        acc[i][j] =
            __builtin_amdgcn_mfma_f32_16x16x32_bf16(af[i], bfr[j], acc[i][j], 0, 0, 0);
  }
#pragma unroll
  for (int i = 0; i < 4; ++i) {
    const int mrow = bm * BM + wm * 64 + i * 16 + (lane >> 4) * 4;
#pragma unroll
    for (int j = 0; j < 4; ++j) {
      const int col = bn * BN + wn * 64 + j * 16 + (lane & 15);
      const float bv = bias[col];
#pragma unroll
      for (int r = 0; r < 4; ++r)
        C[(size_t)(mrow + r) * N + col] = acc[i][j][r] + bv;
    }
  }
}

// ---------------- head GEMM 256x256 (LLC-traffic-halving tile) ---------------
// 512 thr = 8 waves (2M x 4N); wave = 128x64 out (8x4 16x16 frags).
// logits = y[4096][512] * hwb[32000][512]^T + head_b, nontemporal stores.
#define HM 256
#define HN 256

__global__ __launch_bounds__(512, 1) void gemm_head_kernel(
    const unsigned short* __restrict__ A, const unsigned short* __restrict__ B,
    const float* __restrict__ bias, float* __restrict__ C) {
  __shared__ unsigned short a_lds[HM * 32];
  __shared__ unsigned short b_lds[HN * 32];
  const int nbn = VOCAB / HN;  // 125
  const int nwg = gridDim.x;   // 2000
  const int chunk = nwg >> 3;  // 250
  const int bid = blockIdx.x;
  const int sw = (bid & 7) * chunk + (bid >> 3);
  const int bm = sw / nbn, bn = sw % nbn;
  const int tid = threadIdx.x;
  const int lane = tid & 63, wid = tid >> 6;
  const int wm = wid >> 2, wn = wid & 3;

  f32x4 acc[8][4] = {};

  for (int kt = 0; kt < HID / 32; ++kt) {
    __syncthreads();
#pragma unroll
    for (int p = 0; p < 2; ++p) {
      const int flat = (p * 512 + tid) * 16;  // 0..16KB
      const int row = flat >> 6;              // 64B rows (32 bf16)
      const int kb = flat & 63;
      const char* ga =
          (const char*)(A + ((size_t)(bm * HM + row) * HID + kt * 32)) + kb;
      const char* gb =
          (const char*)(B + ((size_t)(bn * HN + row) * HID + kt * 32)) + kb;
      char* la = (char*)a_lds + (size_t)(p * 512 + wid * 64) * 16;
      char* lb = (char*)b_lds + (size_t)(p * 512 + wid * 64) * 16;
      __builtin_amdgcn_global_load_lds(
          (const __attribute__((address_space(1))) void*)ga,
          (__attribute__((address_space(3))) void*)la, 16, 0, 0);
      __builtin_amdgcn_global_load_lds(
          (const __attribute__((address_space(1))) void*)gb,
          (__attribute__((address_space(3))) void*)lb, 16, 0, 0);
    }
    __syncthreads();
    bf16x8 af[8], bfr[4];
#pragma unroll
    for (int i = 0; i < 8; ++i)
      af[i] = *(const bf16x8*)(a_lds + (wm * 128 + i * 16 + (lane & 15)) * 32 +
                               (lane >> 4) * 8);
#pragma unroll
    for (int j = 0; j < 4; ++j)
      bfr[j] = *(const bf16x8*)(b_lds + (wn * 64 + j * 16 + (lane & 15)) * 32 +
                                (lane >> 4) * 8);
#pragma unroll
    for (int i = 0; i < 8; ++i)
#pragma unroll
      for (int j = 0; j < 4; ++j)
        acc[i][j] =
            __builtin_amdgcn_mfma_f32_16x16x32_bf16(af[i], bfr[j], acc[i][j], 0, 0, 0);
  }
#pragma unroll
  for (int i = 0; i < 8; ++i) {
    const int mrow = bm * HM + wm * 128 + i * 16 + (lane >> 4) * 4;
#pragma unroll
    for (int j = 0; j < 4; ++j) {
      const int col = bn * HN + wn * 64 + j * 16 + (lane & 15);
      const float bv = bias[col];
#pragma unroll
      for (int r = 0; r < 4; ++r)
        __builtin_nontemporal_store(acc[i][j][r] + bv,
                                    &C[(size_t)(mrow + r) * VOCAB + col]);
    }
  }
}

// ---------------- persistent GRU scan + heater blocks ------------------------
// Blocks 0..31: r5 flag protocol (best verified). Round-12 micro-opts:
// hot-spin poll (no s_sleep), 6-accumulator MFMA split (halved dep chains),
// __fdividef gate math. Blocks 32..255: pure-VALU heaters (neutral-to-+).
__global__ __launch_bounds__(64, 1) void gru_kernel(
    const float* __restrict__ xg, const float* __restrict__ w_hh,
    const float* __restrict__ b_hh, float* __restrict__ hs,
    unsigned short* h_state, int* flags) {
  if (blockIdx.x >= GRU_WGS) {
    float a0 = (float)(threadIdx.x + 1) * 1.0000001f;
    float c0 = 0.f, c1 = 1.f, c2 = 2.f, c3 = 3.f;
    const float b = 0.9999999f;
    for (int it = 0; it < (1 << 14); ++it) {
#pragma unroll 64
      for (int i = 0; i < 512; ++i) {
        c0 = fmaf(c0, b, a0);
        c1 = fmaf(c1, b, a0);
        c2 = fmaf(c2, b, a0);
        c3 = fmaf(c3, b, a0);
      }
      asm volatile("" :: "v"(c0), "v"(c1), "v"(c2), "v"(c3));
      const int v = __hip_atomic_load(flags, __ATOMIC_RELAXED,
                                      __HIP_MEMORY_SCOPE_AGENT);
      if (v >= SEQ) break;
    }
    return;
  }

  const int wid = blockIdx.x;
  const int lane = threadIdx.x;
  const int col16 = lane & 15;
  const int kq = lane >> 4;

  __shared__ float h_pub[8][16];

  bf16x8 wf[3][16];
#pragma unroll
  for (int g = 0; g < 3; ++g) {
    const float* wr =
        w_hh + (size_t)(g * HID + wid * 16 + col16) * HID + kq * 8;
#pragma unroll
    for (int kk = 0; kk < 16; ++kk) {
      float4 f0 = *(const float4*)(wr + kk * 32);
      float4 f1 = *(const float4*)(wr + kk * 32 + 4);
      bf16x8 v;
      v[0] = (short)f2bf(f0.x); v[1] = (short)f2bf(f0.y);
      v[2] = (short)f2bf(f0.z); v[3] = (short)f2bf(f0.w);
      v[4] = (short)f2bf(f1.x); v[5] = (short)f2bf(f1.y);
      v[6] = (short)f2bf(f1.z); v[7] = (short)f2bf(f1.w);
      wf[g][kk] = v;
    }
  }
  const float bh_r = b_hh[0 * HID + wid * 16 + col16];
  const float bh_z = b_hh[1 * HID + wid * 16 + col16];
  const float bh_n = b_hh[2 * HID + wid * 16 + col16];

  const int abase = col16 * HID + kq * 8;
  const bool realrow = col16 < 8;
  const bool owner = lane < 32;
  const int bbase = kq * 4;

  float xr[4], xz[4], xn[4];
#pragma unroll
  for (int r = 0; r < 4; ++r) { xr[r] = 0.f; xz[r] = 0.f; xn[r] = 0.f; }
  if (owner) {
#pragma unroll
    for (int r = 0; r < 4; ++r) {
      const size_t xo = (size_t)(bbase + r) * SEQ * NG + wid * 16 + col16;
      xr[r] = xg[xo];
      xz[r] = xg[xo + HID];
      xn[r] = xg[xo + 2 * HID];
    }
  }
  float hprev[4] = {0.f, 0.f, 0.f, 0.f};
  int budget = GRU_SPIN_BUDGET;

  for (int t = 0; t < SEQ; ++t) {
    // ---- hot-spin wait for h_t (flags >= t) ----
    while (budget > 0) {
      int v = t;
      if (lane < 32)
        v = __hip_atomic_load(flags + lane * 16, __ATOMIC_RELAXED,
                              __HIP_MEMORY_SCOPE_AGENT);
      if (__ballot(v >= t) == ~0ULL) break;
      --budget;
    }

    const unsigned short* rd = h_state + (size_t)(t & 1) * (16 * HID);
    unsigned short* wpub = h_state + (size_t)((t + 1) & 1) * (16 * HID);

    // ---- bulk-load A fragments (one shot, all independent) ----
    uint64_t hb[32];
#pragma unroll
    for (int kk = 0; kk < 32; ++kk) hb[kk] = 0;
    if (realrow) {
#pragma unroll
      for (int kk = 0; kk < 16; ++kk) {
        const uint64_t* ap = (const uint64_t*)(rd + abase + kk * 32);
        hb[2 * kk] =
            __hip_atomic_load(ap, __ATOMIC_RELAXED, __HIP_MEMORY_SCOPE_AGENT);
        hb[2 * kk + 1] = __hip_atomic_load(ap + 1, __ATOMIC_RELAXED,
                                           __HIP_MEMORY_SCOPE_AGENT);
      }
    }

    // ---- 3 gates x 2 half-chains (6 independent accumulators) ----
    f32x4 ar0 = {0.f, 0.f, 0.f, 0.f}, ar1 = {0.f, 0.f, 0.f, 0.f};
    f32x4 az0 = {0.f, 0.f, 0.f, 0.f}, az1 = {0.f, 0.f, 0.f, 0.f};
    f32x4 an0 = {0.f, 0.f, 0.f, 0.f}, an1 = {0.f, 0.f, 0.f, 0.f};
#pragma unroll
    for (int kk = 0; kk < 16; kk += 2) {
      union { uint64_t u[2]; bf16x8 v; } c0, c1;
      c0.u[0] = hb[2 * kk];     c0.u[1] = hb[2 * kk + 1];
      c1.u[0] = hb[2 * kk + 2]; c1.u[1] = hb[2 * kk + 3];
      ar0 = __builtin_amdgcn_mfma_f32_16x16x32_bf16(c0.v, wf[0][kk], ar0, 0, 0, 0);
      az0 = __builtin_amdgcn_mfma_f32_16x16x32_bf16(c0.v, wf[1][kk], az0, 0, 0, 0);
      an0 = __builtin_amdgcn_mfma_f32_16x16x32_bf16(c0.v, wf[2][kk], an0, 0, 0, 0);
      ar1 = __builtin_amdgcn_mfma_f32_16x16x32_bf16(c1.v, wf[0][kk + 1], ar1, 0, 0, 0);
      az1 = __builtin_amdgcn_mfma_f32_16x16x32_bf16(c1.v, wf[1][kk + 1], az1, 0, 0, 0);
      an1 = __builtin_amdgcn_mfma_f32_16x16x32_bf16(c1.v, wf[2][kk + 1], an1, 0, 0, 0);
    }
    const f32x4 ar = ar0 + ar1, az = az0 + az1, an = an0 + an1;

    // ---- in-register gate math (fast rcp) ----
    float hnew[4];
    if (owner) {
#pragma unroll
      for (int r = 0; r < 4; ++r) {
        const float rg = __fdividef(1.f, 1.f + __expf(-(xr[r] + ar[r] + bh_r)));
        const float zg = __fdividef(1.f, 1.f + __expf(-(xz[r] + az[r] + bh_z)));
        const float a = xn[r] + rg * (an[r] + bh_n);
        const float e2 = __expf(-2.f * fabsf(a));
        const float nn = copysignf(__fdividef(1.f - e2, 1.f + e2), a);
        hnew[r] = (1.f - zg) * nn + zg * hprev[r];
        hprev[r] = hnew[r];
        h_pub[bbase + r][col16] = hnew[r];
      }
    }
    asm volatile("" ::: "memory");
    // ---- barrier-free within-wave transpose + publish ----
    {
      const int tb = lane >> 3;
      const int tc = (lane & 7) * 2;
      const float2 hp = *(const float2*)&h_pub[tb][tc];
      union { unsigned short s[2]; uint32_t u; } pk;
      pk.s[0] = f2bf(hp.x);
      pk.s[1] = f2bf(hp.y);
      uint32_t* dst = (uint32_t*)(wpub + tb * HID + wid * 16 + tc);
      __hip_atomic_store(dst, pk.u, __ATOMIC_RELAXED,
                         __HIP_MEMORY_SCOPE_AGENT);
    }
    asm volatile("s_waitcnt vmcnt(0)" ::: "memory");
    if (lane == 0)
      __hip_atomic_store(flags + wid * 16, t + 1, __ATOMIC_RELAXED,
                         __HIP_MEMORY_SCOPE_AGENT);
    // ---- off-critical-path: hs output + next xg prefetch ----
    if (owner) {
#pragma unroll
      for (int r = 0; r < 4; ++r)
        hs[((size_t)(bbase + r) * SEQ + t) * HID + wid * 16 + col16] = hnew[r];
      if (t + 1 < SEQ) {
#pragma unroll
        for (int r = 0; r < 4; ++r) {
          const size_t xo = (size_t)(bbase + r) * SEQ * NG +
                            (size_t)(t + 1) * NG + wid * 16 + col16;
          xr[r] = xg[xo];
          xz[r] = xg[xo + HID];
          xn[r] = xg[xo + 2 * HID];
        }
      }
    }
  }
}

// ---------------- LayerNorm rows of 512 -> bf16 ------------------------------
__global__ __launch_bounds__(256) void ln_kernel(
    const float* __restrict__ hs, const float* __restrict__ gamma,
    const float* __restrict__ beta, unsigned short* __restrict__ y) {
  const int row = blockIdx.x * 4 + (threadIdx.x >> 6);
  const int lane = threadIdx.x & 63;
  const float* x = hs + (size_t)row * HID + lane * 8;
  float v[8];
  *(float4*)v = *(const float4*)x;
  *(float4*)(v + 4) = *(const float4*)(x + 4);
  float s = 0.f, q = 0.f;
#pragma unroll
  for (int j = 0; j < 8; ++j) { s += v[j]; q += v[j] * v[j]; }
#pragma unroll
  for (int off = 32; off > 0; off >>= 1) {
    s += __shfl_xor(s, off);
    q += __shfl_xor(q, off);
  }
  const float mu = s * (1.f / 512.f);
  const float is = rsqrtf(q * (1.f / 512.f) - mu * mu + LN_EPS);
  const float* gp = gamma + lane * 8;
  const float* bp = beta + lane * 8;
  union { unsigned short o[8]; uint4 u; } pk;
#pragma unroll
  for (int j = 0; j < 8; ++j) pk.o[j] = f2bf((v[j] - mu) * is * gp[j] + bp[j]);
  *(uint4*)(y + (size_t)row * HID + lane * 8) = pk.u;
}

// ---------------- launch -----------------------------------------------------
extern "C" void kernel_launch(void* const* d_in, const int* in_sizes, int n_in,
                              void* d_out, int out_size, void* d_ws,
                              size_t ws_size, hipStream_t stream) {
  const int* ids = (const int*)d_in[0];
  const float* emb = (const float*)d_in[1];
  const float* w_ih = (const float*)d_in[2];
  const float* w_hh = (const float*)d_in[3];
  const float* b_ih = (const float*)d_in[4];
  const float* b_hh = (const float*)d_in[5];
  const float* gamma = (const float*)d_in[6];
  const float* beta = (const float*)d_in[7];
  const float* head_w = (const float*)d_in[8];
  const float* head_b = (const float*)d_in[9];
  float* out = (float*)d_out;

  char* ws = (char*)d_ws;
  size_t off = 0;
  auto alloc = [&](size_t bytes) -> void* {
    void* p = ws + off;
    off = (off + bytes + 255) & ~(size_t)255;
    return p;
  };
  int* flags = (int*)alloc(GRU_WGS * 16 * sizeof(int));
  unsigned short* h_state = (unsigned short*)alloc(2 * 16 * HID * 2);
  unsigned short* A1 = (unsigned short*)alloc((size_t)NB * SEQ * HID * 2);
  unsigned short* wihb = (unsigned short*)alloc((size_t)NG * HID * 2);
  unsigned short* hwb = (unsigned short*)alloc((size_t)VOCAB * HID * 2);
  float* xg = (float*)alloc((size_t)NB * SEQ * NG * 4);
  float* hsb = (float*)alloc((size_t)NB * SEQ * HID * 4);
  unsigned short* yb = (unsigned short*)alloc((size_t)NB * SEQ * HID * 2);

  init_ws_kernel<<<64, 256, 0, stream>>>(h_state, flags);
  conv_bf16_kernel<<<(NG * HID / 4) / 256, 256, 0, stream>>>(w_ih, wihb,
                                                             NG * HID / 4);
  conv_bf16_kernel<<<(VOCAB * HID / 4) / 256, 256, 0, stream>>>(
      head_w, hwb, VOCAB * HID / 4);
  embed_kernel<<<NB * SEQ, 256, 0, stream>>>(ids, emb, A1);
  // xg = A1 * w_ih^T + b_ih : M=4096, N=1536 (grid 384, %8==0)
  gemm_bt_kernel<<<(NB * SEQ / BM) * (NG / BN), 256, 0, stream>>>(
      A1, wihb, b_ih, xg, NG, NG / BN);
  // GRU (blocks 0..31) + heaters (32..255)
  gru_kernel<<<GRU_WGS + HEATERS, 64, 0, stream>>>(xg, w_hh, b_hh, hsb,
                                                   h_state, flags);
  ln_kernel<<<NB * SEQ / 4, 256, 0, stream>>>(hsb, gamma, beta, yb);
  // logits = y * hwb^T + head_b : 256x256 tiles, grid 16*125=2000 (%8==0)
  gemm_head_kernel<<<(NB * SEQ / HM) * (VOCAB / HN), 512, 0, stream>>>(
      yb, hwb, head_b, out);
}

// Round 13
// 1687.877 us; speedup vs baseline: 1.0218x; 1.0218x over previous
//
#include <hip/hip_runtime.h>
#include <hip/hip_bf16.h>
#include <stdint.h>

#define VOCAB 32000
#define HID 512
#define NB 8
#define SEQ 512
#define NG 1536
#define LN_EPS 1e-5f
#define GRU_WGS 32
#define HEATERS 224
#define GRU_SPIN_BUDGET (1 << 20)

typedef short bf16x8 __attribute__((ext_vector_type(8)));
typedef float f32x4 __attribute__((ext_vector_type(4)));

__device__ __forceinline__ unsigned short f2bf(float f) {
  union { float f; uint32_t u; } c; c.f = f;
  return (unsigned short)((c.u + 0x7fffu + ((c.u >> 16) & 1u)) >> 16);
}

// ---------------- init workspace (every launch: h_state=0, flags=0) ---------
__global__ void init_ws_kernel(unsigned short* h_state, int* flags) {
  int i = blockIdx.x * 256 + threadIdx.x;
  if (i < 2 * 16 * HID) h_state[i] = 0;
  if (i < GRU_WGS * 16) flags[i] = 0;
}

// ---------------- fp32 -> bf16 bulk convert ---------------------------------
__global__ void conv_bf16_kernel(const float* __restrict__ in,
                                 unsigned short* __restrict__ out, int n4) {
  int i = blockIdx.x * 256 + threadIdx.x;
  if (i >= n4) return;
  const float4 v = ((const float4*)in)[i];
  ushort4 o;
  o.x = f2bf(v.x); o.y = f2bf(v.y); o.z = f2bf(v.z); o.w = f2bf(v.w);
  ((ushort4*)out)[i] = o;
}

// ---------------- embedding gather -> bf16 A matrix [4096][512] -------------
__global__ void embed_kernel(const int* __restrict__ ids,
                             const float* __restrict__ emb,
                             unsigned short* __restrict__ out) {
  int row = blockIdx.x;
  int id = ids[row];
  int c = threadIdx.x * 2;
  const float2 v = *(const float2*)(emb + (size_t)id * HID + c);
  ushort2 o; o.x = f2bf(v.x); o.y = f2bf(v.y);
  *(ushort2*)(out + (size_t)row * HID + c) = o;
}

// ---------------- bf16 GEMM 128x128 (xg GEMM) --------------------------------
#define BM 128
#define BN 128
#define BK 32

__global__ __launch_bounds__(256, 2) void gemm_bt_kernel(
    const unsigned short* __restrict__ A, const unsigned short* __restrict__ B,
    const float* __restrict__ bias, float* __restrict__ C, int N, int nbn) {
  __shared__ unsigned short a_lds[BM * BK];
  __shared__ unsigned short b_lds[BN * BK];
  const int nwg = gridDim.x;
  const int chunk = nwg >> 3;
  const int bid = blockIdx.x;
  const int sw = (bid & 7) * chunk + (bid >> 3);
  const int bm = sw / nbn, bn = sw % nbn;
  const int tid = threadIdx.x;
  const int lane = tid & 63, wid = tid >> 6;
  const int wm = wid >> 1, wn = wid & 1;

  f32x4 acc[4][4] = {};

  for (int kt = 0; kt < HID / BK; ++kt) {
    __syncthreads();
#pragma unroll
    for (int p = 0; p < 2; ++p) {
      const int flat = (p * 256 + tid) * 16;
      const int row = flat >> 6;
      const int kb = flat & 63;
      const char* ga =
          (const char*)(A + ((size_t)(bm * BM + row) * HID + kt * BK)) + kb;
      const char* gb =
          (const char*)(B + ((size_t)(bn * BN + row) * HID + kt * BK)) + kb;
      char* la = (char*)a_lds + (size_t)(p * 256 + wid * 64) * 16;
      char* lb = (char*)b_lds + (size_t)(p * 256 + wid * 64) * 16;
      __builtin_amdgcn_global_load_lds(
          (const __attribute__((address_space(1))) void*)ga,
          (__attribute__((address_space(3))) void*)la, 16, 0, 0);
      __builtin_amdgcn_global_load_lds(
          (const __attribute__((address_space(1))) void*)gb,
          (__attribute__((address_space(3))) void*)lb, 16, 0, 0);
    }
    __syncthreads();
    bf16x8 af[4], bfr[4];
#pragma unroll
    for (int i = 0; i < 4; ++i) {
      af[i] = *(const bf16x8*)(a_lds + (wm * 64 + i * 16 + (lane & 15)) * BK +
                               (lane >> 4) * 8);
      bfr[i] = *(const bf16x8*)(b_lds + (wn * 64 + i * 16 + (lane & 15)) * BK +
                                (lane >> 4) * 8);
    }
#pragma unroll
    for (int i = 0; i < 4; ++i)
#pragma unroll
      for (int j = 0; j < 4; ++j)
        acc[i][j] =
            __builtin_amdgcn_mfma_f32_16x16x32_bf16(af[i], bfr[j], acc[i][j], 0, 0, 0);
  }
#pragma unroll
  for (int i = 0; i < 4; ++i) {
    const int mrow = bm * BM + wm * 64 + i * 16 + (lane >> 4) * 4;
#pragma unroll
    for (int j = 0; j < 4; ++j) {
      const int col = bn * BN + wn * 64 + j * 16 + (lane & 15);
      const float bv = bias[col];
#pragma unroll
      for (int r = 0; r < 4; ++r)
        C[(size_t)(mrow + r) * N + col] = acc[i][j][r] + bv;
    }
  }
}

// ---------------- head GEMM 256x256 (LLC-traffic-halving tile) ---------------
#define HM 256
#define HN 256

__global__ __launch_bounds__(512, 1) void gemm_head_kernel(
    const unsigned short* __restrict__ A, const unsigned short* __restrict__ B,
    const float* __restrict__ bias, float* __restrict__ C) {
  __shared__ unsigned short a_lds[HM * 32];
  __shared__ unsigned short b_lds[HN * 32];
  const int nbn = VOCAB / HN;  // 125
  const int nwg = gridDim.x;   // 2000
  const int chunk = nwg >> 3;  // 250
  const int bid = blockIdx.x;
  const int sw = (bid & 7) * chunk + (bid >> 3);
  const int bm = sw / nbn, bn = sw % nbn;
  const int tid = threadIdx.x;
  const int lane = tid & 63, wid = tid >> 6;
  const int wm = wid >> 2, wn = wid & 3;

  f32x4 acc[8][4] = {};

  for (int kt = 0; kt < HID / 32; ++kt) {
    __syncthreads();
#pragma unroll
    for (int p = 0; p < 2; ++p) {
      const int flat = (p * 512 + tid) * 16;
      const int row = flat >> 6;
      const int kb = flat & 63;
      const char* ga =
          (const char*)(A + ((size_t)(bm * HM + row) * HID + kt * 32)) + kb;
      const char* gb =
          (const char*)(B + ((size_t)(bn * HN + row) * HID + kt * 32)) + kb;
      char* la = (char*)a_lds + (size_t)(p * 512 + wid * 64) * 16;
      char* lb = (char*)b_lds + (size_t)(p * 512 + wid * 64) * 16;
      __builtin_amdgcn_global_load_lds(
          (const __attribute__((address_space(1))) void*)ga,
          (__attribute__((address_space(3))) void*)la, 16, 0, 0);
      __builtin_amdgcn_global_load_lds(
          (const __attribute__((address_space(1))) void*)gb,
          (__attribute__((address_space(3))) void*)lb, 16, 0, 0);
    }
    __syncthreads();
    bf16x8 af[8], bfr[4];
#pragma unroll
    for (int i = 0; i < 8; ++i)
      af[i] = *(const bf16x8*)(a_lds + (wm * 128 + i * 16 + (lane & 15)) * 32 +
                               (lane >> 4) * 8);
#pragma unroll
    for (int j = 0; j < 4; ++j)
      bfr[j] = *(const bf16x8*)(b_lds + (wn * 64 + j * 16 + (lane & 15)) * 32 +
                                (lane >> 4) * 8);
#pragma unroll
    for (int i = 0; i < 8; ++i)
#pragma unroll
      for (int j = 0; j < 4; ++j)
        acc[i][j] =
            __builtin_amdgcn_mfma_f32_16x16x32_bf16(af[i], bfr[j], acc[i][j], 0, 0, 0);
  }
#pragma unroll
  for (int i = 0; i < 8; ++i) {
    const int mrow = bm * HM + wm * 128 + i * 16 + (lane >> 4) * 4;
#pragma unroll
    for (int j = 0; j < 4; ++j) {
      const int col = bn * HN + wn * 64 + j * 16 + (lane & 15);
      const float bv = bias[col];
#pragma unroll
      for (int r = 0; r < 4; ++r)
        __builtin_nontemporal_store(acc[i][j][r] + bv,
                                    &C[(size_t)(mrow + r) * VOCAB + col]);
    }
  }
}

// ---------------- persistent GRU scan + heater blocks ------------------------
// Blocks 0..31: round-11-VERBATIM GRU (r5 flag protocol, s_sleep(1) poll —
// hot-spin regressed it in r12: extra poll traffic congests the same fabric
// the publishes traverse). Blocks 32..255: pure-VALU heaters.
__global__ __launch_bounds__(64, 1) void gru_kernel(
    const float* __restrict__ xg, const float* __restrict__ w_hh,
    const float* __restrict__ b_hh, float* __restrict__ hs,
    unsigned short* h_state, int* flags) {
  if (blockIdx.x >= GRU_WGS) {
    // ---- heater ----
    float a0 = (float)(threadIdx.x + 1) * 1.0000001f;
    float c0 = 0.f, c1 = 1.f, c2 = 2.f, c3 = 3.f;
    const float b = 0.9999999f;
    for (int it = 0; it < (1 << 14); ++it) {
#pragma unroll 64
      for (int i = 0; i < 512; ++i) {
        c0 = fmaf(c0, b, a0);
        c1 = fmaf(c1, b, a0);
        c2 = fmaf(c2, b, a0);
        c3 = fmaf(c3, b, a0);
      }
      asm volatile("" :: "v"(c0), "v"(c1), "v"(c2), "v"(c3));
      const int v = __hip_atomic_load(flags, __ATOMIC_RELAXED,
                                      __HIP_MEMORY_SCOPE_AGENT);
      if (v >= SEQ) break;
    }
    return;
  }

  const int wid = blockIdx.x;
  const int lane = threadIdx.x;
  const int col16 = lane & 15;
  const int kq = lane >> 4;  // 0..3 : which 8-wide K slice of the 32-window

  __shared__ float h_pub[8][16];

  // pack all 3 gates' weights into 48 MFMA B-fragments (registers), once
  bf16x8 wf[3][16];
#pragma unroll
  for (int g = 0; g < 3; ++g) {
    const float* wr =
        w_hh + (size_t)(g * HID + wid * 16 + col16) * HID + kq * 8;
#pragma unroll
    for (int kk = 0; kk < 16; ++kk) {
      float4 f0 = *(const float4*)(wr + kk * 32);
      float4 f1 = *(const float4*)(wr + kk * 32 + 4);
      bf16x8 v;
      v[0] = (short)f2bf(f0.x); v[1] = (short)f2bf(f0.y);
      v[2] = (short)f2bf(f0.z); v[3] = (short)f2bf(f0.w);
      v[4] = (short)f2bf(f1.x); v[5] = (short)f2bf(f1.y);
      v[6] = (short)f2bf(f1.z); v[7] = (short)f2bf(f1.w);
      wf[g][kk] = v;
    }
  }
  const float bh_r = b_hh[0 * HID + wid * 16 + col16];
  const float bh_z = b_hh[1 * HID + wid * 16 + col16];
  const float bh_n = b_hh[2 * HID + wid * 16 + col16];

  const int abase = col16 * HID + kq * 8;  // A-frag: row=batch=col16, k=kq*8
  const bool realrow = col16 < 8;          // batches 8..15 are padding zeros
  const bool owner = lane < 32;            // lanes 0..31 own real (batch,col)
  const int bbase = kq * 4;                // first batch of this lane's C rows

  // per-lane xg for 4 batches (prefetched); lanes>=32 unused
  float xr[4], xz[4], xn[4];
#pragma unroll
  for (int r = 0; r < 4; ++r) { xr[r] = 0.f; xz[r] = 0.f; xn[r] = 0.f; }
  if (owner) {
#pragma unroll
    for (int r = 0; r < 4; ++r) {
      const size_t xo = (size_t)(bbase + r) * SEQ * NG + wid * 16 + col16;
      xr[r] = xg[xo];
      xz[r] = xg[xo + HID];
      xn[r] = xg[xo + 2 * HID];
    }
  }
  float hprev[4] = {0.f, 0.f, 0.f, 0.f};
  int budget = GRU_SPIN_BUDGET;

  for (int t = 0; t < SEQ; ++t) {
    // ---- wait for h_t (flags >= t); all 64 lanes in the ballot ----
    while (budget > 0) {
      int v = t;
      if (lane < 32)
        v = __hip_atomic_load(flags + lane * 16, __ATOMIC_RELAXED,
                              __HIP_MEMORY_SCOPE_AGENT);
      if (__ballot(v >= t) == ~0ULL) break;
      --budget;
      __builtin_amdgcn_s_sleep(1);
    }

    const unsigned short* rd = h_state + (size_t)(t & 1) * (16 * HID);
    unsigned short* wpub = h_state + (size_t)((t + 1) & 1) * (16 * HID);

    // ---- bulk-load A fragments (one shot, all independent) ----
    uint64_t hb[32];
#pragma unroll
    for (int kk = 0; kk < 32; ++kk) hb[kk] = 0;
    if (realrow) {
#pragma unroll
      for (int kk = 0; kk < 16; ++kk) {
        const uint64_t* ap = (const uint64_t*)(rd + abase + kk * 32);
        hb[2 * kk] =
            __hip_atomic_load(ap, __ATOMIC_RELAXED, __HIP_MEMORY_SCOPE_AGENT);
        hb[2 * kk + 1] = __hip_atomic_load(ap + 1, __ATOMIC_RELAXED,
                                           __HIP_MEMORY_SCOPE_AGENT);
      }
    }

    // ---- three independent 16-deep MFMA chains (r, z, n) ----
    f32x4 ar = {0.f, 0.f, 0.f, 0.f};
    f32x4 az = {0.f, 0.f, 0.f, 0.f};
    f32x4 an = {0.f, 0.f, 0.f, 0.f};
#pragma unroll
    for (int kk = 0; kk < 16; ++kk) {
      union { uint64_t u[2]; bf16x8 v; } cv;
      cv.u[0] = hb[2 * kk]; cv.u[1] = hb[2 * kk + 1];
      ar = __builtin_amdgcn_mfma_f32_16x16x32_bf16(cv.v, wf[0][kk], ar, 0, 0, 0);
      az = __builtin_amdgcn_mfma_f32_16x16x32_bf16(cv.v, wf[1][kk], az, 0, 0, 0);
      an = __builtin_amdgcn_mfma_f32_16x16x32_bf16(cv.v, wf[2][kk], an, 0, 0, 0);
    }

    // ---- in-register gate math: lane owns (batch bbase+r, col col16) ----
    float hnew[4];
    if (owner) {
#pragma unroll
      for (int r = 0; r < 4; ++r) {
        const float rg = 1.f / (1.f + __expf(-(xr[r] + ar[r] + bh_r)));
        const float zg = 1.f / (1.f + __expf(-(xz[r] + az[r] + bh_z)));
        const float a = xn[r] + rg * (an[r] + bh_n);
        const float e2 = __expf(-2.f * fabsf(a));
        const float nn = copysignf((1.f - e2) / (1.f + e2), a);
        hnew[r] = (1.f - zg) * nn + zg * hprev[r];
        hprev[r] = hnew[r];
        h_pub[bbase + r][col16] = hnew[r];
      }
    }
    asm volatile("" ::: "memory");  // keep ds_writes before ds_reads
    // ---- barrier-free within-wave transpose + publish ----
    {
      const int tb = lane >> 3;          // batch 0..7
      const int tc = (lane & 7) * 2;     // even col of the pair
      const float2 hp = *(const float2*)&h_pub[tb][tc];
      union { unsigned short s[2]; uint32_t u; } pk;
      pk.s[0] = f2bf(hp.x);
      pk.s[1] = f2bf(hp.y);
      uint32_t* dst = (uint32_t*)(wpub + tb * HID + wid * 16 + tc);
      __hip_atomic_store(dst, pk.u, __ATOMIC_RELAXED,
                         __HIP_MEMORY_SCOPE_AGENT);
    }
    asm volatile("s_waitcnt vmcnt(0)" ::: "memory");  // drain publish stores
    if (lane == 0)
      __hip_atomic_store(flags + wid * 16, t + 1, __ATOMIC_RELAXED,
                         __HIP_MEMORY_SCOPE_AGENT);
    // ---- off-critical-path: hs output + next xg prefetch ----
    if (owner) {
#pragma unroll
      for (int r = 0; r < 4; ++r)
        hs[((size_t)(bbase + r) * SEQ + t) * HID + wid * 16 + col16] = hnew[r];
      if (t + 1 < SEQ) {
#pragma unroll
        for (int r = 0; r < 4; ++r) {
          const size_t xo = (size_t)(bbase + r) * SEQ * NG +
                            (size_t)(t + 1) * NG + wid * 16 + col16;
          xr[r] = xg[xo];
          xz[r] = xg[xo + HID];
          xn[r] = xg[xo + 2 * HID];
        }
      }
    }
  }
}

// ---------------- LayerNorm rows of 512 -> bf16 ------------------------------
__global__ __launch_bounds__(256) void ln_kernel(
    const float* __restrict__ hs, const float* __restrict__ gamma,
    const float* __restrict__ beta, unsigned short* __restrict__ y) {
  const int row = blockIdx.x * 4 + (threadIdx.x >> 6);
  const int lane = threadIdx.x & 63;
  const float* x = hs + (size_t)row * HID + lane * 8;
  float v[8];
  *(float4*)v = *(const float4*)x;
  *(float4*)(v + 4) = *(const float4*)(x + 4);
  float s = 0.f, q = 0.f;
#pragma unroll
  for (int j = 0; j < 8; ++j) { s += v[j]; q += v[j] * v[j]; }
#pragma unroll
  for (int off = 32; off > 0; off >>= 1) {
    s += __shfl_xor(s, off);
    q += __shfl_xor(q, off);
  }
  const float mu = s * (1.f / 512.f);
  const float is = rsqrtf(q * (1.f / 512.f) - mu * mu + LN_EPS);
  const float* gp = gamma + lane * 8;
  const float* bp = beta + lane * 8;
  union { unsigned short o[8]; uint4 u; } pk;
#pragma unroll
  for (int j = 0; j < 8; ++j) pk.o[j] = f2bf((v[j] - mu) * is * gp[j] + bp[j]);
  *(uint4*)(y + (size_t)row * HID + lane * 8) = pk.u;
}

// ---------------- launch -----------------------------------------------------
extern "C" void kernel_launch(void* const* d_in, const int* in_sizes, int n_in,
                              void* d_out, int out_size, void* d_ws,
                              size_t ws_size, hipStream_t stream) {
  const int* ids = (const int*)d_in[0];
  const float* emb = (const float*)d_in[1];
  const float* w_ih = (const float*)d_in[2];
  const float* w_hh = (const float*)d_in[3];
  const float* b_ih = (const float*)d_in[4];
  const float* b_hh = (const float*)d_in[5];
  const float* gamma = (const float*)d_in[6];
  const float* beta = (const float*)d_in[7];
  const float* head_w = (const float*)d_in[8];
  const float* head_b = (const float*)d_in[9];
  float* out = (float*)d_out;

  char* ws = (char*)d_ws;
  size_t off = 0;
  auto alloc = [&](size_t bytes) -> void* {
    void* p = ws + off;
    off = (off + bytes + 255) & ~(size_t)255;
    return p;
  };
  int* flags = (int*)alloc(GRU_WGS * 16 * sizeof(int));
  unsigned short* h_state = (unsigned short*)alloc(2 * 16 * HID * 2);
  unsigned short* A1 = (unsigned short*)alloc((size_t)NB * SEQ * HID * 2);
  unsigned short* wihb = (unsigned short*)alloc((size_t)NG * HID * 2);
  unsigned short* hwb = (unsigned short*)alloc((size_t)VOCAB * HID * 2);
  float* xg = (float*)alloc((size_t)NB * SEQ * NG * 4);
  float* hsb = (float*)alloc((size_t)NB * SEQ * HID * 4);
  unsigned short* yb = (unsigned short*)alloc((size_t)NB * SEQ * HID * 2);

  init_ws_kernel<<<64, 256, 0, stream>>>(h_state, flags);
  conv_bf16_kernel<<<(NG * HID / 4) / 256, 256, 0, stream>>>(w_ih, wihb,
                                                             NG * HID / 4);
  conv_bf16_kernel<<<(VOCAB * HID / 4) / 256, 256, 0, stream>>>(
      head_w, hwb, VOCAB * HID / 4);
  embed_kernel<<<NB * SEQ, 256, 0, stream>>>(ids, emb, A1);
  // xg = A1 * w_ih^T + b_ih : M=4096, N=1536  (grid 32*12=384, %8==0)
  gemm_bt_kernel<<<(NB * SEQ / BM) * (NG / BN), 256, 0, stream>>>(
      A1, wihb, b_ih, xg, NG, NG / BN);
  // GRU (blocks 0..31, r11-verbatim) + heaters (32..255)
  gru_kernel<<<GRU_WGS + HEATERS, 64, 0, stream>>>(xg, w_hh, b_hh, hsb,
                                                   h_state, flags);
  ln_kernel<<<NB * SEQ / 4, 256, 0, stream>>>(hsb, gamma, beta, yb);
  // logits = y * hwb^T + head_b : 256x256 tiles, grid 16*125=2000 (%8==0)
  gemm_head_kernel<<<(NB * SEQ / HM) * (VOCAB / HN), 512, 0, stream>>>(
      yb, hwb, head_b, out);
}